// Round 1
// 180.040 us; speedup vs baseline: 1.1020x; 1.1020x over previous
//
#include <hip/hip_runtime.h>

typedef _Float16 half4  __attribute__((ext_vector_type(4)));
typedef _Float16 half8  __attribute__((ext_vector_type(8)));
typedef float    f32x4  __attribute__((ext_vector_type(4)));

#define EC 768   // per-wave LDS edge-index capacity for layer-1 chain-break

// ---------------- emb gather role: one half8 chunk per thread ---------------------
__device__ __forceinline__ void gather_dev(const int* __restrict__ ent,
                                           const float* __restrict__ emb,
                                           _Float16* __restrict__ X, int gb, int N) {
  int t = gb * 256 + threadIdx.x;
  if (t >= N * 16) return;
  int node = t >> 4, g = t & 15;
  const float4* s = (const float4*)(emb + (long)ent[node] * 128 + g * 8);
  float4 a = s[0], c = s[1];
  half8 o;
  o[0] = (_Float16)a.x; o[1] = (_Float16)a.y; o[2] = (_Float16)a.z; o[3] = (_Float16)a.w;
  o[4] = (_Float16)c.x; o[5] = (_Float16)c.y; o[6] = (_Float16)c.z; o[7] = (_Float16)c.w;
  *(half8*)(X + (long)t * 8) = o;
}

// B-frag order: lane holds B[kt*32+(lane>>4)*8+j][nt*16+(lane&15)], j=0..7.
__device__ __forceinline__ void pack_dev(const float* Wa, const float* Wb,
                                         _Float16* out, int NT, int ncols, int t) {
  int lane = t & 63, tile = t >> 6;
  int nt = tile % NT, kt = tile / NT;
  int n  = nt * 16 + (lane & 15);
  int kb = kt * 32 + (lane >> 4) * 8;
  half8 o;
#pragma unroll
  for (int j = 0; j < 8; ++j) {
    int k = kb + j;
    float w = (k < 128) ? Wa[k * ncols + n] : Wb[(k - 128) * ncols + n];
    o[j] = (_Float16)w;
  }
  *(half8*)(out + (long)t * 8) = o;
}

// ---------------- phase 1: count+rank (single atomic pass) ∥ gather ∥ packs -------
// rank[e] = old value of deg[dst[e]] — captured here so the later fill pass needs
// NO atomics (csr slot = row_off[d] + rank[e] is unique by construction).
__global__ __launch_bounds__(256) void countrank_k(
    const int* __restrict__ dst, int* __restrict__ deg, int* __restrict__ rnk,
    const int* __restrict__ ent, const float* __restrict__ emb, _Float16* __restrict__ X,
    const float* __restrict__ W1l, const float* __restrict__ W1r, _Float16* __restrict__ Wp1,
    const float* __restrict__ W2l, const float* __restrict__ W2r, const float* __restrict__ Wc,
    _Float16* __restrict__ Wz, const float* __restrict__ b2, const float* __restrict__ bc,
    float* __restrict__ bpr, int N, int E, int IB1) {
  int b = blockIdx.x;
  if (b < IB1) {                                   // 1:1 count/gather interleave
    if (b & 1) {
      gather_dev(ent, emb, X, b >> 1, N);
    } else {
      int t = (b >> 1) * 256 + threadIdx.x;
      if (t < E) { int d = dst[t]; rnk[t] = atomicAdd(&deg[d], 1); }
    }
  } else if (b < IB1 + 16) {                       // W1 concat pack (KT=8, NT=8)
    pack_dev(W1l, W1r, Wp1, 8, 128, (b - IB1) * 256 + threadIdx.x);
  } else if (b < IB1 + 32) {                       // Wz fold: one elem/thread
    int i = (b - IB1 - 16) * 256 + threadIdx.x;    // packed element index, 4096 total
    int j = i & 7, lane = (i >> 3) & 63, tile = i >> 9;
    int nt = tile & 1, kt = tile >> 1;
    int k = kt * 32 + (lane >> 4) * 8 + j;
    int c = lane & 15;
    const float* W = nt ? W2r : W2l;
    float s = 0.f;
#pragma unroll 8
    for (int q = 0; q < 128; ++q) s += W[k * 128 + q] * Wc[q * 16 + c];
    Wz[i] = (_Float16)s;
  } else {                                         // b' = b2@Wc + bc
    int n = threadIdx.x;
    if (n < 16) {
      float s = bc[n];
      for (int k = 0; k < 128; ++k) s += b2[k] * Wc[k * 16 + n];
      bpr[n] = s;
    }
  }
}

// ---------------- scan step 1: per-block degree sums (+ gather ballast) -----------
__global__ __launch_bounds__(256) void deg_part_k(
    const int* __restrict__ deg, int* __restrict__ part, int N, int NBP,
    const int* __restrict__ ent, const float* __restrict__ emb,
    _Float16* __restrict__ X, int goff) {
  int b = blockIdx.x;
  if (b >= NBP) { gather_dev(ent, emb, X, goff + b - NBP, N); return; }
  int t = b * 256 + threadIdx.x;
  int v = (t < N) ? deg[t] : 0;
  v += __shfl_down(v, 32); v += __shfl_down(v, 16); v += __shfl_down(v, 8);
  v += __shfl_down(v, 4);  v += __shfl_down(v, 2);  v += __shfl_down(v, 1);
  __shared__ int sm[4];
  if ((threadIdx.x & 63) == 0) sm[threadIdx.x >> 6] = v;
  __syncthreads();
  if (threadIdx.x == 0) part[b] = sm[0] + sm[1] + sm[2] + sm[3];
}

// ---------------- scan step 2: row offsets (+ gather ballast) ---------------------
__global__ __launch_bounds__(256) void row_off_k(
    const int* __restrict__ deg, const int* __restrict__ part,
    int* __restrict__ row_off, int N, int NBv,
    const int* __restrict__ ent, const float* __restrict__ emb,
    _Float16* __restrict__ X, int goff) {
  int b = blockIdx.x;
  if (b >= NBv) { gather_dev(ent, emb, X, goff + b - NBv, N); return; }
  __shared__ int ps[256];
  __shared__ int sm[256];
  int tl = threadIdx.x;
  int pv = (tl < NBv) ? part[tl] : 0;
  ps[tl] = pv; __syncthreads();
  for (int off = 1; off < 256; off <<= 1) {
    int a = ps[tl]; int bb = (tl >= off) ? ps[tl - off] : 0;
    __syncthreads(); ps[tl] = a + bb; __syncthreads();
  }
  int chunk_off = (b > 0) ? ps[b - 1] : 0;
  if (b == 0 && tl == 255) row_off[N] = ps[255];
  int t = b * 256 + tl;
  int v = (t < N) ? deg[t] : 0;
  sm[tl] = v; __syncthreads();
  for (int off = 1; off < 256; off <<= 1) {
    int a = sm[tl]; int bb = (tl >= off) ? sm[tl - off] : 0;
    __syncthreads(); sm[tl] = a + bb; __syncthreads();
  }
  if (t < N) row_off[t] = chunk_off + sm[tl] - v;
}

// ---------------- phase 3: NON-ATOMIC CSR scatter (+ remaining gather, 6:1) -------
__global__ __launch_bounds__(256) void fill_k(
    const int* __restrict__ src, const int* __restrict__ dst,
    const int* __restrict__ rnk, const int* __restrict__ row_off,
    int* __restrict__ csr,
    const int* __restrict__ ent, const float* __restrict__ emb,
    _Float16* __restrict__ X, int E, int N, int FB, int goff) {
  int b = blockIdx.x, per = b / 7, ph = b % 7;
  if (ph < 6) {
    int fb = per * 6 + ph;
    if (fb >= FB) return;
    int t = fb * 256 + threadIdx.x;
    if (t < E) csr[row_off[dst[t]] + rnk[t]] = src[t];
  } else {
    gather_dev(ent, emb, X, goff + per, N);        // t-guard handles overshoot
  }
}

// ---------------- layer-1 gather+mean into LDS tile (16 rows x 128, stride 136) ----
__device__ __forceinline__ void agg_to_lds(const _Float16* __restrict__ X,
                                           const int* __restrict__ row_off,
                                           const int* __restrict__ csr,
                                           _Float16* ab, int* eidx,
                                           int row0, int M, int lane) {
  int nd_end = min(row0 + 16, M);
  int ebeg = row_off[row0 < M ? row0 : M - 1];
  int eend = row_off[nd_end];
  int cnt  = eend - ebeg;
  bool fits = (cnt <= EC);
  if (fits)
    for (int i = lane; i < cnt; i += 64) eidx[i] = csr[ebeg + i];
  int g = lane >> 4, j = lane & 15;
#pragma unroll
  for (int batch = 0; batch < 4; ++batch) {
    int node = row0 + batch * 4 + g;
    int nc = (node < M) ? node : M - 1;
    int beg = row_off[nc], end = row_off[nc + 1];
    half8 acc = (half8)(_Float16)0.f;
    if (fits) {
      const int* ix = eidx + (beg - ebeg);
      int n = end - beg;
#pragma unroll 8
      for (int e = 0; e < n; ++e) {
        half8 v = *(const half8*)(X + (long)ix[e] * 128 + j * 8);
        acc += v;
      }
    } else {
#pragma unroll 8
      for (int e = beg; e < end; ++e) {
        half8 v = *(const half8*)(X + (long)csr[e] * 128 + j * 8);
        acc += v;
      }
    }
    _Float16 inv = (_Float16)(1.f / fmaxf((float)(end - beg), 1.f));
    acc *= (half8)inv;
    *(half8*)(ab + (batch * 4 + g) * 136 + j * 8) = acc;
  }
}

// ---------------- fused layer-1 + folded layer-2 GEMM ------------------------------
__global__ __launch_bounds__(128) void gemm1z_k(const _Float16* __restrict__ X,
                                                const int* __restrict__ row_off,
                                                const int* __restrict__ csr,
                                                const _Float16* __restrict__ Bp,
                                                const float* __restrict__ bias,
                                                const _Float16* __restrict__ Bz,
                                                const float* __restrict__ bprime,
                                                _Float16* __restrict__ Zl,
                                                float* __restrict__ Pr, int M) {
  __shared__ _Float16 abuf[2][16 * 136];
  __shared__ int      ebuf[2][EC];
  int wave = threadIdx.x >> 6, lane = threadIdx.x & 63;
  _Float16* ab = abuf[wave];
  int row0 = blockIdx.x * 32 + wave * 16;
  agg_to_lds(X, row_off, csr, ab, ebuf[wave], row0, M, lane);
  int m = lane & 15, quad = lane >> 4;
  int arow = row0 + m; if (arow > M - 1) arow = M - 1;
  f32x4 acc[8];
#pragma unroll
  for (int i = 0; i < 8; ++i) acc[i] = (f32x4){0.f, 0.f, 0.f, 0.f};
#pragma unroll
  for (int kt = 0; kt < 8; ++kt) {
    half8 af = (kt < 4) ? *(const half8*)(ab + m * 136 + kt * 32 + quad * 8)
                        : *(const half8*)(X + (long)arow * 128 + (kt - 4) * 32 + quad * 8);
#pragma unroll
    for (int nt = 0; nt < 8; ++nt) {
      half8 bf = *(const half8*)(Bp + ((long)(kt * 8 + nt) * 64 + lane) * 8);
      acc[nt] = __builtin_amdgcn_mfma_f32_16x16x32_f16(af, bf, acc[nt], 0, 0, 0);
    }
  }
  // h1 tile: +b1, relu, stage into ab (agg contents dead; same f16 rounding as before)
#pragma unroll
  for (int nt = 0; nt < 8; ++nt) {
    float bv = bias[nt * 16 + m];
#pragma unroll
    for (int r = 0; r < 4; ++r)
      ab[(quad * 4 + r) * 136 + nt * 16 + m] = (_Float16)fmaxf(acc[nt][r] + bv, 0.f);
  }
  // folded layer-2: Zl = h1@W2lc, Pr = h1@W2rc + b'
  f32x4 a0 = (f32x4){0.f, 0.f, 0.f, 0.f}, a1 = a0;
#pragma unroll
  for (int kt = 0; kt < 4; ++kt) {
    half8 af = *(const half8*)(ab + m * 136 + kt * 32 + quad * 8);
    half8 b0 = *(const half8*)(Bz + ((long)(kt * 2 + 0) * 64 + lane) * 8);
    half8 b1 = *(const half8*)(Bz + ((long)(kt * 2 + 1) * 64 + lane) * 8);
    a0 = __builtin_amdgcn_mfma_f32_16x16x32_f16(af, b0, a0, 0, 0, 0);
    a1 = __builtin_amdgcn_mfma_f32_16x16x32_f16(af, b1, a1, 0, 0, 0);
  }
  float bv = bprime[m];
#pragma unroll
  for (int r = 0; r < 4; ++r) {
    int orow = row0 + quad * 4 + r;
    if (orow < M) {
      Zl[(long)orow * 16 + m] = (_Float16)a0[r];
      Pr[(long)orow * 16 + m] = a1[r] + bv;
    }
  }
}

// ---------------- final: out = mean_agg(Zl) + Pr --------------------------------
__global__ __launch_bounds__(256) void aggout_k(const _Float16* __restrict__ Zl,
                                                const float* __restrict__ Pr,
                                                const int* __restrict__ row_off,
                                                const int* __restrict__ csr,
                                                float* __restrict__ out, int M) {
  int t = blockIdx.x * 256 + threadIdx.x;
  int node = t >> 2, q = t & 3;
  if (node >= M) return;
  int beg = row_off[node], end = row_off[node + 1];
  float a0 = 0.f, a1 = 0.f, a2 = 0.f, a3 = 0.f;
#pragma unroll 8
  for (int e = beg; e < end; ++e) {
    half4 v = *(const half4*)(Zl + (long)csr[e] * 16 + q * 4);
    a0 += (float)v[0]; a1 += (float)v[1]; a2 += (float)v[2]; a3 += (float)v[3];
  }
  float inv = 1.f / fmaxf((float)(end - beg), 1.f);
  long o = (long)node * 16 + q * 4;
  const float4 pv = *(const float4*)(Pr + o);
  float4 ov;
  ov.x = a0 * inv + pv.x; ov.y = a1 * inv + pv.y;
  ov.z = a2 * inv + pv.z; ov.w = a3 * inv + pv.w;
  *(float4*)(out + o) = ov;
}

extern "C" void kernel_launch(void* const* d_in, const int* in_sizes, int n_in,
                              void* d_out, int out_size, void* d_ws, size_t ws_size,
                              hipStream_t stream) {
  const int N = in_sizes[0];
  const int E = in_sizes[1] / 2;
  const int*   entity = (const int*)d_in[0];
  const int*   e_src  = (const int*)d_in[1];
  const int*   e_dst  = e_src + E;
  const float* emb    = (const float*)d_in[2];
  const float* W1l    = (const float*)d_in[3];
  const float* b1     = (const float*)d_in[4];
  const float* W1r    = (const float*)d_in[5];
  const float* W2l    = (const float*)d_in[6];
  const float* b2     = (const float*)d_in[7];
  const float* W2r    = (const float*)d_in[8];
  const float* Wc     = (const float*)d_in[9];
  const float* bc     = (const float*)d_in[10];
  float* out = (float*)d_out;

  // workspace layout (cur[] replaced by rank[E])
  char* p = (char*)d_ws;
  _Float16* x0  = (_Float16*)p; p += (size_t)N * 128 * 2;
  _Float16* Wp1 = (_Float16*)p; p += 256 * 128 * 2;
  _Float16* Wz  = (_Float16*)p; p += 128 * 32 * 2;
  float*    bpr = (float*)p;    p += 16 * 4;
  _Float16* Zl  = (_Float16*)p; p += (size_t)N * 16 * 2;
  float*    Pr  = (float*)p;    p += (size_t)N * 16 * 4;
  int* deg     = (int*)p; p += (size_t)N * 4;
  int* rnk     = (int*)p; p += (size_t)E * 4;
  int* row_off = (int*)p; p += (size_t)(N + 1) * 4;
  int* csr     = (int*)p; p += (size_t)E * 4;
  int* part    = (int*)p; p += 1024 * 4;

  const int NB = (N + 255) / 256;          // 196 scan blocks
  const int CB = (E + 255) / 256;          // 2344 count/fill blocks
  const int GB = (N * 16 + 255) / 256;     // 3125 gather blocks total

  // distribute gather across all idle phases
  int G1  = CB < GB ? CB : GB;             // 1:1 with count (atomic-latency shadow)
  int rem = GB - G1;
  int GS1 = rem > 192 ? 192 : rem; rem -= GS1;   // ballast in deg_part
  int GS2 = rem > 192 ? 192 : rem; rem -= GS2;   // ballast in row_off
  int G2  = rem;                                  // remainder rides the fill pass
  int per3 = (CB + 5) / 6; if (per3 < G2) per3 = G2;

  hipMemsetAsync(deg, 0, (size_t)N * 4, stream);

  // phase 1: count+rank (the ONLY atomic pass) ∥ gather ∥ weight packs
  countrank_k<<<2 * CB + 33, 256, 0, stream>>>(e_dst, deg, rnk, entity, emb, x0,
                                               W1l, W1r, Wp1, W2l, W2r, Wc, Wz,
                                               b2, bc, bpr, N, E, 2 * CB);
  // phase 2: two-level exclusive scan of degrees (+ gather ballast)
  deg_part_k<<<NB + GS1, 256, 0, stream>>>(deg, part, N, NB, entity, emb, x0, G1);
  row_off_k<<<NB + GS2, 256, 0, stream>>>(deg, part, row_off, N, NB,
                                          entity, emb, x0, G1 + GS1);
  // phase 3: non-atomic CSR scatter (+ remaining gather, 6:1)
  fill_k<<<7 * per3, 256, 0, stream>>>(e_src, e_dst, rnk, row_off, csr,
                                       entity, emb, x0, E, N, CB, G1 + GS1 + GS2);
  // fused: h1 = relu([mean_agg(x0)|x0]@Wp1+b1) -> Zl = h1@W2lc, Pr = h1@W2rc + b'
  gemm1z_k<<<(N + 31) / 32, 128, 0, stream>>>(x0, row_off, csr, Wp1, b1,
                                              Wz, bpr, Zl, Pr, N);
  // out = mean_agg(Zl) + Pr   (32 B/edge gather)
  aggout_k<<<(N * 4 + 255) / 256, 256, 0, stream>>>(Zl, Pr, row_off, csr, out, N);
}

// Round 2
// 160.127 us; speedup vs baseline: 1.2391x; 1.1244x over previous
//
#include <hip/hip_runtime.h>

typedef _Float16 half4  __attribute__((ext_vector_type(4)));
typedef _Float16 half8  __attribute__((ext_vector_type(8)));
typedef float    f32x4  __attribute__((ext_vector_type(4)));

#define EC 768      // per-wave LDS edge-index capacity for layer-1 chain-break
#define CAP 4096    // bucket capacity (edges); E/NBUCK ~ 3061, ~17 sigma margin
#define CHUNK 1536  // edges per pass-A block (6 per thread)

// ---------------- emb gather role: one half8 chunk per thread ---------------------
__device__ __forceinline__ void gather_dev(const int* __restrict__ ent,
                                           const float* __restrict__ emb,
                                           _Float16* __restrict__ X, int gb, int N) {
  int t = gb * 256 + threadIdx.x;
  if (t >= N * 16) return;
  int node = t >> 4, g = t & 15;
  const float4* s = (const float4*)(emb + (long)ent[node] * 128 + g * 8);
  float4 a = s[0], c = s[1];
  half8 o;
  o[0] = (_Float16)a.x; o[1] = (_Float16)a.y; o[2] = (_Float16)a.z; o[3] = (_Float16)a.w;
  o[4] = (_Float16)c.x; o[5] = (_Float16)c.y; o[6] = (_Float16)c.z; o[7] = (_Float16)c.w;
  *(half8*)(X + (long)t * 8) = o;
}

// B-frag order: lane holds B[kt*32+(lane>>4)*8+j][nt*16+(lane&15)], j=0..7.
__device__ __forceinline__ void pack_dev(const float* Wa, const float* Wb,
                                         _Float16* out, int NT, int ncols, int t) {
  int lane = t & 63, tile = t >> 6;
  int nt = tile % NT, kt = tile / NT;
  int n  = nt * 16 + (lane & 15);
  int kb = kt * 32 + (lane >> 4) * 8;
  half8 o;
#pragma unroll
  for (int j = 0; j < 8; ++j) {
    int k = kb + j;
    float w = (k < 128) ? Wa[k * ncols + n] : Wb[(k - 128) * ncols + n];
    o[j] = (_Float16)w;
  }
  *(half8*)(out + (long)t * 8) = o;
}

// ---------------- pass A: LDS-histogram bucket scatter ∥ gather ∥ packs -----------
// Edges binned by dst>>8 into fixed CAP regions. Per (block,bin) ONE global atomic
// (space allocation); per-edge rank comes from the LDS histogram atomic's return.
// Packed word: (src<<8)|(dst&255) — 4 B/edge (requires N < 2^23).
__global__ __launch_bounds__(256) void bucketA_k(
    const int* __restrict__ src, const int* __restrict__ dst,
    int* __restrict__ cur, int* __restrict__ buck,
    const int* __restrict__ ent, const float* __restrict__ emb, _Float16* __restrict__ X,
    const float* __restrict__ W1l, const float* __restrict__ W1r, _Float16* __restrict__ Wp1,
    const float* __restrict__ W2l, const float* __restrict__ W2r, const float* __restrict__ Wc,
    _Float16* __restrict__ Wz, const float* __restrict__ b2, const float* __restrict__ bc,
    float* __restrict__ bpr, int N, int E, int NA, int NBUCK, int ST, int IBA) {
  int b = blockIdx.x;
  if (b < IBA) {
    int grp = b / ST, ph = b % ST;
    if (ph != 0) { gather_dev(ent, emb, X, grp * (ST - 1) + ph - 1, N); return; }
    __shared__ int lbin[256], gbase[256];
    int tl = threadIdx.x;
    lbin[tl] = 0; __syncthreads();
    int e0 = grp * CHUNK;
    int pk[6], bn[6], lr[6];
#pragma unroll
    for (int k = 0; k < 6; ++k) {
      int e = e0 + k * 256 + tl;
      bn[k] = -1;
      if (e < E) {
        int d = dst[e];
        bn[k] = d >> 8;
        pk[k] = (src[e] << 8) | (d & 255);
        lr[k] = atomicAdd(&lbin[bn[k]], 1);
      }
    }
    __syncthreads();
    gbase[tl] = (tl < NBUCK && lbin[tl]) ? atomicAdd(&cur[tl], lbin[tl]) : 0;
    __syncthreads();
#pragma unroll
    for (int k = 0; k < 6; ++k) {
      if (bn[k] >= 0) {
        int idx = gbase[bn[k]] + lr[k];
        if (idx < CAP) buck[(long)bn[k] * CAP + idx] = pk[k];
      }
    }
  } else if (b < IBA + 16) {                       // W1 concat pack (KT=8, NT=8)
    pack_dev(W1l, W1r, Wp1, 8, 128, (b - IBA) * 256 + threadIdx.x);
  } else if (b < IBA + 32) {                       // Wz fold: one elem/thread
    int i = (b - IBA - 16) * 256 + threadIdx.x;    // packed element index, 4096 total
    int j = i & 7, lane = (i >> 3) & 63, tile = i >> 9;
    int nt = tile & 1, kt = tile >> 1;
    int k = kt * 32 + (lane >> 4) * 8 + j;
    int c = lane & 15;
    const float* W = nt ? W2r : W2l;
    float s = 0.f;
#pragma unroll 8
    for (int q = 0; q < 128; ++q) s += W[k * 128 + q] * Wc[q * 16 + c];
    Wz[i] = (_Float16)s;
  } else {                                         // b' = b2@Wc + bc
    int n = threadIdx.x;
    if (n < 16) {
      float s = bc[n];
      for (int k = 0; k < 128; ++k) s += b2[k] * Wc[k * 16 + n];
      bpr[n] = s;
    }
  }
}

// ---------------- pass B: per-bucket degree+scan+rank, writes row_off & csr -------
// One block per bucket (256 nodes). No global atomics at all.
__global__ __launch_bounds__(256) void bucketB_k(
    const int* __restrict__ cur, const int* __restrict__ buck,
    int* __restrict__ row_off, int* __restrict__ csr, int N, int E, int NBUCK) {
  int B0 = blockIdx.x, tl = threadIdx.x;
  __shared__ int sA[256], cnt[256], sB[256], run[256];
  // exclusive prefix of bucket sizes -> this bucket's global edge base
  sA[tl] = (tl < NBUCK) ? cur[tl] : 0; __syncthreads();
  for (int off = 1; off < 256; off <<= 1) {
    int a = sA[tl], bb = (tl >= off) ? sA[tl - off] : 0;
    __syncthreads(); sA[tl] = a + bb; __syncthreads();
  }
  int bsz = cur[B0]; if (bsz > CAP) bsz = CAP;
  int ebase = sA[B0] - bsz;
  // per-node counts (LDS atomics)
  cnt[tl] = 0; __syncthreads();
  const int* bp = buck + (long)B0 * CAP;
  for (int i = tl; i < bsz; i += 256) atomicAdd(&cnt[bp[i] & 255], 1);
  __syncthreads();
  // exclusive scan -> local row offsets
  int cv = cnt[tl];
  sB[tl] = cv; __syncthreads();
  for (int off = 1; off < 256; off <<= 1) {
    int a = sB[tl], bb = (tl >= off) ? sB[tl - off] : 0;
    __syncthreads(); sB[tl] = a + bb; __syncthreads();
  }
  int loff = sB[tl] - cv;
  int node = (B0 << 8) + tl;
  if (node < N) row_off[node] = ebase + loff;
  if (B0 == 0 && tl == 0) row_off[N] = E;
  run[tl] = loff; __syncthreads();
  // rank + scatter into csr (writes stay within this bucket's contiguous region)
  for (int i = tl; i < bsz; i += 256) {
    int w = bp[i];
    int r = atomicAdd(&run[w & 255], 1);
    csr[ebase + r] = w >> 8;
  }
}

// ---------------- layer-1 gather+mean into LDS tile (16 rows x 128, stride 136) ----
__device__ __forceinline__ void agg_to_lds(const _Float16* __restrict__ X,
                                           const int* __restrict__ row_off,
                                           const int* __restrict__ csr,
                                           _Float16* ab, int* eidx,
                                           int row0, int M, int lane) {
  int nd_end = min(row0 + 16, M);
  int ebeg = row_off[row0 < M ? row0 : M - 1];
  int eend = row_off[nd_end];
  int cnt  = eend - ebeg;
  bool fits = (cnt <= EC);
  if (fits)
    for (int i = lane; i < cnt; i += 64) eidx[i] = csr[ebeg + i];
  int g = lane >> 4, j = lane & 15;
#pragma unroll
  for (int batch = 0; batch < 4; ++batch) {
    int node = row0 + batch * 4 + g;
    int nc = (node < M) ? node : M - 1;
    int beg = row_off[nc], end = row_off[nc + 1];
    half8 acc = (half8)(_Float16)0.f;
    if (fits) {
      const int* ix = eidx + (beg - ebeg);
      int n = end - beg;
#pragma unroll 8
      for (int e = 0; e < n; ++e) {
        half8 v = *(const half8*)(X + (long)ix[e] * 128 + j * 8);
        acc += v;
      }
    } else {
#pragma unroll 8
      for (int e = beg; e < end; ++e) {
        half8 v = *(const half8*)(X + (long)csr[e] * 128 + j * 8);
        acc += v;
      }
    }
    _Float16 inv = (_Float16)(1.f / fmaxf((float)(end - beg), 1.f));
    acc *= (half8)inv;
    *(half8*)(ab + (batch * 4 + g) * 136 + j * 8) = acc;
  }
}

// ---------------- fused layer-1 + folded layer-2 GEMM ------------------------------
__global__ __launch_bounds__(128) void gemm1z_k(const _Float16* __restrict__ X,
                                                const int* __restrict__ row_off,
                                                const int* __restrict__ csr,
                                                const _Float16* __restrict__ Bp,
                                                const float* __restrict__ bias,
                                                const _Float16* __restrict__ Bz,
                                                const float* __restrict__ bprime,
                                                _Float16* __restrict__ Zl,
                                                float* __restrict__ Pr, int M) {
  __shared__ _Float16 abuf[2][16 * 136];
  __shared__ int      ebuf[2][EC];
  int wave = threadIdx.x >> 6, lane = threadIdx.x & 63;
  _Float16* ab = abuf[wave];
  int row0 = blockIdx.x * 32 + wave * 16;
  agg_to_lds(X, row_off, csr, ab, ebuf[wave], row0, M, lane);
  int m = lane & 15, quad = lane >> 4;
  int arow = row0 + m; if (arow > M - 1) arow = M - 1;
  f32x4 acc[8];
#pragma unroll
  for (int i = 0; i < 8; ++i) acc[i] = (f32x4){0.f, 0.f, 0.f, 0.f};
#pragma unroll
  for (int kt = 0; kt < 8; ++kt) {
    half8 af = (kt < 4) ? *(const half8*)(ab + m * 136 + kt * 32 + quad * 8)
                        : *(const half8*)(X + (long)arow * 128 + (kt - 4) * 32 + quad * 8);
#pragma unroll
    for (int nt = 0; nt < 8; ++nt) {
      half8 bf = *(const half8*)(Bp + ((long)(kt * 8 + nt) * 64 + lane) * 8);
      acc[nt] = __builtin_amdgcn_mfma_f32_16x16x32_f16(af, bf, acc[nt], 0, 0, 0);
    }
  }
  // h1 tile: +b1, relu, stage into ab (agg contents dead; same f16 rounding as before)
#pragma unroll
  for (int nt = 0; nt < 8; ++nt) {
    float bv = bias[nt * 16 + m];
#pragma unroll
    for (int r = 0; r < 4; ++r)
      ab[(quad * 4 + r) * 136 + nt * 16 + m] = (_Float16)fmaxf(acc[nt][r] + bv, 0.f);
  }
  // folded layer-2: Zl = h1@W2lc, Pr = h1@W2rc + b'
  f32x4 a0 = (f32x4){0.f, 0.f, 0.f, 0.f}, a1 = a0;
#pragma unroll
  for (int kt = 0; kt < 4; ++kt) {
    half8 af = *(const half8*)(ab + m * 136 + kt * 32 + quad * 8);
    half8 b0 = *(const half8*)(Bz + ((long)(kt * 2 + 0) * 64 + lane) * 8);
    half8 b1 = *(const half8*)(Bz + ((long)(kt * 2 + 1) * 64 + lane) * 8);
    a0 = __builtin_amdgcn_mfma_f32_16x16x32_f16(af, b0, a0, 0, 0, 0);
    a1 = __builtin_amdgcn_mfma_f32_16x16x32_f16(af, b1, a1, 0, 0, 0);
  }
  float bv = bprime[m];
#pragma unroll
  for (int r = 0; r < 4; ++r) {
    int orow = row0 + quad * 4 + r;
    if (orow < M) {
      Zl[(long)orow * 16 + m] = (_Float16)a0[r];
      Pr[(long)orow * 16 + m] = a1[r] + bv;
    }
  }
}

// ---------------- final: out = mean_agg(Zl) + Pr --------------------------------
__global__ __launch_bounds__(256) void aggout_k(const _Float16* __restrict__ Zl,
                                                const float* __restrict__ Pr,
                                                const int* __restrict__ row_off,
                                                const int* __restrict__ csr,
                                                float* __restrict__ out, int M) {
  int t = blockIdx.x * 256 + threadIdx.x;
  int node = t >> 2, q = t & 3;
  if (node >= M) return;
  int beg = row_off[node], end = row_off[node + 1];
  float a0 = 0.f, a1 = 0.f, a2 = 0.f, a3 = 0.f;
#pragma unroll 8
  for (int e = beg; e < end; ++e) {
    half4 v = *(const half4*)(Zl + (long)csr[e] * 16 + q * 4);
    a0 += (float)v[0]; a1 += (float)v[1]; a2 += (float)v[2]; a3 += (float)v[3];
  }
  float inv = 1.f / fmaxf((float)(end - beg), 1.f);
  long o = (long)node * 16 + q * 4;
  const float4 pv = *(const float4*)(Pr + o);
  float4 ov;
  ov.x = a0 * inv + pv.x; ov.y = a1 * inv + pv.y;
  ov.z = a2 * inv + pv.z; ov.w = a3 * inv + pv.w;
  *(float4*)(out + o) = ov;
}

extern "C" void kernel_launch(void* const* d_in, const int* in_sizes, int n_in,
                              void* d_out, int out_size, void* d_ws, size_t ws_size,
                              hipStream_t stream) {
  const int N = in_sizes[0];
  const int E = in_sizes[1] / 2;
  const int*   entity = (const int*)d_in[0];
  const int*   e_src  = (const int*)d_in[1];
  const int*   e_dst  = e_src + E;
  const float* emb    = (const float*)d_in[2];
  const float* W1l    = (const float*)d_in[3];
  const float* b1     = (const float*)d_in[4];
  const float* W1r    = (const float*)d_in[5];
  const float* W2l    = (const float*)d_in[6];
  const float* b2     = (const float*)d_in[7];
  const float* W2r    = (const float*)d_in[8];
  const float* Wc     = (const float*)d_in[9];
  const float* bc     = (const float*)d_in[10];
  float* out = (float*)d_out;

  const int NBUCK = (N + 255) >> 8;        // 196 buckets of 256 nodes

  // workspace layout (deg/rnk eliminated; buck added)
  char* p = (char*)d_ws;
  _Float16* x0  = (_Float16*)p; p += (size_t)N * 128 * 2;
  _Float16* Wp1 = (_Float16*)p; p += 256 * 128 * 2;
  _Float16* Wz  = (_Float16*)p; p += 128 * 32 * 2;
  float*    bpr = (float*)p;    p += 16 * 4;
  _Float16* Zl  = (_Float16*)p; p += (size_t)N * 16 * 2;
  float*    Pr  = (float*)p;    p += (size_t)N * 16 * 4;
  int* cur     = (int*)p; p += (size_t)NBUCK * 4;
  int* row_off = (int*)p; p += (size_t)(N + 1) * 4;
  int* csr     = (int*)p; p += (size_t)E * 4;
  int* buck    = (int*)p; p += (size_t)NBUCK * CAP * 4;

  const int NA = (E + CHUNK - 1) / CHUNK;  // 391 pass-A work blocks
  const int GB = (N * 16 + 255) / 256;     // 3125 gather blocks
  const int GAper = (GB + NA - 1) / NA;    // gathers per A-block (8)
  const int ST  = GAper + 1;               // interleave stride
  const int IBA = ST * NA;                 // interleaved region

  hipMemsetAsync(cur, 0, (size_t)NBUCK * 4, stream);

  // pass A: bucket scatter (77K global atomics total) ∥ full emb gather ∥ packs
  bucketA_k<<<IBA + 33, 256, 0, stream>>>(e_src, e_dst, cur, buck,
                                          entity, emb, x0, W1l, W1r, Wp1,
                                          W2l, W2r, Wc, Wz, b2, bc, bpr,
                                          N, E, NA, NBUCK, ST, IBA);
  // pass B: per-bucket degree+scan+rank -> row_off, csr (LDS only)
  bucketB_k<<<NBUCK, 256, 0, stream>>>(cur, buck, row_off, csr, N, E, NBUCK);
  // fused: h1 = relu([mean_agg(x0)|x0]@Wp1+b1) -> Zl = h1@W2lc, Pr = h1@W2rc + b'
  gemm1z_k<<<(N + 31) / 32, 128, 0, stream>>>(x0, row_off, csr, Wp1, b1,
                                              Wz, bpr, Zl, Pr, N);
  // out = mean_agg(Zl) + Pr   (32 B/edge gather)
  aggout_k<<<(N * 4 + 255) / 256, 256, 0, stream>>>(Zl, Pr, row_off, csr, out, N);
}